// Round 7
// baseline (201.886 us; speedup 1.0000x reference)
//
#include <hip/hip_runtime.h>
#include <math.h>

// Round 13: R12 skeleton (142us), LDS-op diet. R12 proved VALU is not the
// binding pipe (VALU count -11% -> time flat); arithmetic puts the LDS pipe
// at ~80-90% busy. Three layout changes cut LDS wave-ops ~25%:
//   1. s_bits as redundant uint4 entries (entry[py] = words py..py+3):
//      conv's 3x ds_read_b32 -> 1x broadcast ds_read_b128. Enc packs via
//      24 lanes (word j = (w>>2)+(w&3), select from wave-uniform ballots).
//   2. s_p channel-interleaved pairs {ch0[j],ch1[j]} at 20*(j/9)+2*(j%9):
//      conv's 2x ds_write_b32 -> 1x ds_write_b64; chunks stay 16B-aligned.
//   3. lin reads 9x b64 -> 4x b128 + 1x b64; weights re-paired
//      {W[lo][9lq+t], W[lo][36+9lq+t]} (summation reorder, same class as
//      R12's pk pairing).
// Gathers (8x b128/conv) untouched: pair-LUT alternative needs 32KB ->
// occupancy 16->6 waves/CU, rejected. Skeleton: G=6 steps/barrier, 16-deep
// buffers, 4+2 conv split, shfl quad-reduce, 2-group-deferred stores.
// Requires T % 6 == 0, T >= 18.

typedef float v2f __attribute__((ext_vector_type(2)));

__global__ __launch_bounds__(128, 4) void snn_step_kernel(
    const float* __restrict__ x,       // [B,1,15,15]
    const float* __restrict__ conv_w,  // [2,1,4,4]
    const float* __restrict__ conv_b,  // [2]
    const float* __restrict__ lin_w,   // [10,72]
    const float* __restrict__ lin_b,   // [10]
    float* __restrict__ out,           // spk_out[B,10] ++ mem_rec[T,B,10] ++ spk_rec[T,B,10]
    int T, int B)
{
    const int b   = blockIdx.x;
    const int tid = threadIdx.x;
    const int w   = tid & 63;
    const int wv  = tid >> 6;   // 0 = enc + 4conv, 1 = 2conv + lin + dec

    __shared__ float    s_linw[720];
    __shared__ float    s_linb[10];
    __shared__ float4   s_lut[4][32];    // [ky][5-bit row bits] -> 4 partial sums
    __shared__ uint4    s_bits4[16][8];  // entries 0..5 used: [py] = words py..py+3
    __shared__ float    s_p[16][80];     // pair j at [20*(j/9) + 2*(j%9)]

    // ---- cooperative staging (128 threads) ----
    for (int j = tid; j < 720; j += 128) s_linw[j] = lin_w[j];
    if (tid < 10) s_linb[tid] = lin_b[tid];
    {
        const int ky = tid >> 5, n = tid & 31;
        float s00 = 0.f, s01 = 0.f, s10 = 0.f, s11 = 0.f;
#pragma unroll
        for (int kx = 0; kx < 4; ++kx) {
            const float w0 = conv_w[ky * 4 + kx];        // ch0
            const float w1 = conv_w[16 + ky * 4 + kx];   // ch1
            if ((n >> kx) & 1)       { s00 += w0; s01 += w1; }  // dx = 0
            if ((n >> (kx + 1)) & 1) { s10 += w0; s11 += w1; }  // dx = 1
        }
        s_lut[ky][n] = make_float4(s00, s01, s10, s11);
    }
    __syncthreads();

    // ===== encoder state (wave0 only; wave1 lanes hold zeros), packed =====
    v2f ve01 = (v2f){0.f, 0.f}, ve23 = (v2f){0.f, 0.f};
    v2f cur01, cur23;
    {
        const int jrow = w >> 4, col = w & 15;
        float c[4];
#pragma unroll
        for (int k = 0; k < 4; ++k) {
            const int  row = 4 * k + jrow;
            const bool act = (col < 15) && (row < 15) && (wv == 0);
            c[k] = act ? __fmul_rn(x[(size_t)b * 225 + row * 15 + col], 10.0f) : 0.f;
        }
        cur01 = (v2f){c[0], c[1]};
        cur23 = (v2f){c[2], c[3]};
    }

    // enc word-pack lane params: lanes 0..23 write word jword of the slot
    const int  jword   = (w >> 2) + (w & 3);   // 0..8 (8 -> pad, zeroed)
    const bool wr_bits = (w < 24);

    // ===== conv lane params (used by both waves) =====
    const bool convlane = (w < 36);
    const int  py = w / 6, px = w - 6 * py;
    const int  wordsel = py;                 // entry py = words py..py+2 (+pad)
    const int  shx = 2 * px, shx16 = shx + 16;
    const int  poff = 20 * (w / 9) + 2 * (w - 9 * (w / 9));  // pair write offset
    const v2f  cb2 = (v2f){conv_b[0], conv_b[1]};

    // ===== lin/decoder lane params (wave1) =====
    const int lo = w >> 2, lq = w & 3;
    v2f lw2[9];   // lw2[t] = {W[lo][9lq+t], W[lo][36+9lq+t]} (interleaved pairs)
#pragma unroll
    for (int t = 0; t < 9; ++t) {
        int i0 = lo * 72 + 9 * lq + t;
        int i1 = i0 + 36;
        lw2[t] = (v2f){s_linw[i0 < 720 ? i0 : 719],
                       s_linw[i1 < 720 ? i1 : 719]};   // clamp for lanes >= 40
    }
    const float lbias = s_linb[lo < 10 ? lo : 0];
    float v = 0.f, i_syn = 0.f, sc = 0.f;
    float svv[6], svs[6];
    const size_t BO = (size_t)B * 10;
    float* mp  = out + BO + (size_t)b * 10 + lo;
    float* spp = out + BO + (size_t)T * BO + (size_t)b * 10 + lo;

    // encoder step (packed update) + ballot word-pack -> s_bits4[slot]
    auto enc_pack = [&](int slot) {
        const v2f tenth = (v2f){0.1f, 0.1f};
        v2f vn01 = ve01 + (cur01 - ve01) * tenth;   // pk sub/mul/add: IEEE per half
        v2f vn23 = ve23 + (cur23 - ve23) * tenth;
        bool sp0 = (vn01.x > 1.0f);
        bool sp1 = (vn01.y > 1.0f);
        bool sp2 = (vn23.x > 1.0f);
        bool sp3 = (vn23.y > 1.0f);
        unsigned long long bal0 = __ballot(sp0);
        unsigned long long bal1 = __ballot(sp1);
        unsigned long long bal2 = __ballot(sp2);
        unsigned long long bal3 = __ballot(sp3);
        ve01 = (v2f){sp0 ? 0.f : vn01.x, sp1 ? 0.f : vn01.y};
        ve23 = (v2f){sp2 ? 0.f : vn23.x, sp3 ? 0.f : vn23.y};
        // wave-uniform ballots; lane picks word jword (jh tree hoisted per lane)
        const int jh = jword >> 1;                  // 0..4
        unsigned long long m01 = (jh & 1) ? bal1 : bal0;
        unsigned long long m23 = (jh & 1) ? bal3 : bal2;
        unsigned long long m   = (jh & 2) ? m23 : m01;
        unsigned word = (unsigned)((jword & 1) ? (m >> 32) : m);
        word = (jword < 8) ? word : 0u;             // entry 5's pad word
        if (wr_bits) ((unsigned*)&s_bits4[slot][0])[w] = word;
    };

    // conv LUT compute from pre-read words -> interleaved pair in s_p[slot]
    auto conv_compute = [&](int slot, unsigned wb0, unsigned wb1, unsigned wb2) {
        const int i0 = (wb0 >> shx)   & 31;
        const int i1 = (wb0 >> shx16) & 31;
        const int i2 = (wb1 >> shx)   & 31;
        const int i3 = (wb1 >> shx16) & 31;
        const int i4 = (wb2 >> shx)   & 31;

        const float4 f0 = s_lut[0][i0];
        const float4 f1 = s_lut[1][i1];
        const float4 f2 = s_lut[2][i2];
        const float4 f3 = s_lut[3][i3];
        const float4 g0 = s_lut[0][i1];
        const float4 g1 = s_lut[1][i2];
        const float4 g2 = s_lut[2][i3];
        const float4 g3 = s_lut[3][i4];

        v2f a00 = (v2f){f0.x, f0.y};  a00 += (v2f){f1.x, f1.y};
        a00 += (v2f){f2.x, f2.y};     a00 += (v2f){f3.x, f3.y};
        v2f a01 = (v2f){f0.z, f0.w};  a01 += (v2f){f1.z, f1.w};
        a01 += (v2f){f2.z, f2.w};     a01 += (v2f){f3.z, f3.w};
        v2f a10 = (v2f){g0.x, g0.y};  a10 += (v2f){g1.x, g1.y};
        a10 += (v2f){g2.x, g2.y};     a10 += (v2f){g3.x, g3.y};
        v2f a11 = (v2f){g0.z, g0.w};  a11 += (v2f){g1.z, g1.w};
        a11 += (v2f){g2.z, g2.w};     a11 += (v2f){g3.z, g3.w};

        v2f mraw = __builtin_elementwise_max(
                       __builtin_elementwise_max(a00, a01),
                       __builtin_elementwise_max(a10, a11));
        v2f m2 = mraw + cb2;   // bias after max: rn(x+b) monotone -> exact

        *(v2f*)&s_p[slot][poff] = m2;   // one ds_write_b64: pair {ch0, ch1}
    };

    // linear (packed fma over interleaved pairs) + decoder; deferred slot k
    auto lin_dec = [&](int s, int k) {
        const float* base = &s_p[s & 15][lq * 20];
        float4 q0 = *(const float4*)(base + 0);
        float4 q1 = *(const float4*)(base + 4);
        float4 q2 = *(const float4*)(base + 8);
        float4 q3 = *(const float4*)(base + 12);
        v2f    q4 = *(const v2f*)(base + 16);
        v2f pacc = (v2f){0.f, 0.f};
        pacc = __builtin_elementwise_fma(lw2[0], (v2f){q0.x, q0.y}, pacc);
        pacc = __builtin_elementwise_fma(lw2[1], (v2f){q0.z, q0.w}, pacc);
        pacc = __builtin_elementwise_fma(lw2[2], (v2f){q1.x, q1.y}, pacc);
        pacc = __builtin_elementwise_fma(lw2[3], (v2f){q1.z, q1.w}, pacc);
        pacc = __builtin_elementwise_fma(lw2[4], (v2f){q2.x, q2.y}, pacc);
        pacc = __builtin_elementwise_fma(lw2[5], (v2f){q2.z, q2.w}, pacc);
        pacc = __builtin_elementwise_fma(lw2[6], (v2f){q3.x, q3.y}, pacc);
        pacc = __builtin_elementwise_fma(lw2[7], (v2f){q3.z, q3.w}, pacc);
        pacc = __builtin_elementwise_fma(lw2[8], q4, pacc);
        float partial = __fadd_rn(pacc.x, pacc.y);

        // quad reduce (((p0+p1)+p2)+p3)+lbias
        float p1 = __shfl_xor(partial, 1);
        float p2 = __shfl_xor(partial, 2);
        float p3 = __shfl_xor(partial, 3);
        float lin = __fadd_rn(
            __fadd_rn(__fadd_rn(__fadd_rn(partial, p1), p2), p3), lbias);

        float vd  = __fadd_rn(v, __fmul_rn(0.1f, __fsub_rn(i_syn, v)));
        float id  = __fsub_rn(i_syn, __fmul_rn(0.2f, i_syn));
        float spk = (vd > 1.0f) ? 1.0f : 0.0f;
        v = (vd > 1.0f) ? 0.0f : vd;
        sc += spk;
        svv[k] = v;
        svs[k] = spk;
        i_syn = __fadd_rn(id, lin);
    };

    auto issue_stores = [&]() {
        if (lq == 0 && lo < 10) {
#pragma unroll
            for (int k = 0; k < 6; ++k) {
                mp[(size_t)k * BO]  = svv[k];
                spp[(size_t)k * BO] = svs[k];
            }
        }
        mp  += 6 * BO;
        spp += 6 * BO;
    };

    // ---- prologue: enc(0) -> bits[0] ----
    if (wv == 0) enc_pack(0);

    const int NG = T / 6;   // T % 6 == 0

    for (int g = 0; g < NG; ++g) {
        const int base = 6 * g;
        if (wv == 0) {
#pragma unroll
            for (int k = 0; k < 4; ++k) {
                const int s = base + k;
                uint4 bb = make_uint4(0, 0, 0, 0);
                if (convlane) bb = s_bits4[s & 15][wordsel];   // 1x b128
                enc_pack((s + 1) & 15);              // enc hides the bit read
                if (convlane) conv_compute(s & 15, bb.x, bb.y, bb.z);
            }
            enc_pack((base + 5) & 15);
            enc_pack((base + 6) & 15);
        } else {
            if (g >= 2) issue_stores();              // group g-2
            if (g >= 1) {
                const int pb = base - 6;
                // conv for steps pb+4, pb+5 (bits from group g-1, barrier-safe)
                if (convlane) {
                    uint4 ba = s_bits4[(pb + 4) & 15][wordsel];
                    uint4 bc = s_bits4[(pb + 5) & 15][wordsel];
                    conv_compute((pb + 4) & 15, ba.x, ba.y, ba.z);
                    conv_compute((pb + 5) & 15, bc.x, bc.y, bc.z);
                }
#pragma unroll
                for (int k = 0; k < 6; ++k)          // lin+dec group g-1
                    lin_dec(pb + k, k);
            }
        }
        __syncthreads();
    }

    // ---- epilogue (wave1): stores NG-2, conv+lin+dec NG-1, stores NG-1 ----
    if (wv == 1) {
        issue_stores();                              // group NG-2
        const int pb = 6 * (NG - 1);
        if (convlane) {
            uint4 ba = s_bits4[(pb + 4) & 15][wordsel];
            uint4 bc = s_bits4[(pb + 5) & 15][wordsel];
            conv_compute((pb + 4) & 15, ba.x, ba.y, ba.z);
            conv_compute((pb + 5) & 15, bc.x, bc.y, bc.z);
        }
#pragma unroll
        for (int k = 0; k < 6; ++k)
            lin_dec(pb + k, k);
        issue_stores();                              // group NG-1
        if (lq == 0 && lo < 10) out[(size_t)b * 10 + lo] = sc;
    }
}

extern "C" void kernel_launch(void* const* d_in, const int* in_sizes, int n_in,
                              void* d_out, int out_size, void* d_ws, size_t ws_size,
                              hipStream_t stream) {
    const float* x      = (const float*)d_in[0];
    const float* conv_w = (const float*)d_in[1];
    const float* conv_b = (const float*)d_in[2];
    const float* lin_w  = (const float*)d_in[3];
    const float* lin_b  = (const float*)d_in[4];
    float* out = (float*)d_out;

    const int B = in_sizes[0] / 225;             // x is [B,1,15,15]
    const int T = (out_size / (B * 10) - 1) / 2; // out = B*10 * (1 + 2T); T=300

    snn_step_kernel<<<B, 128, 0, stream>>>(x, conv_w, conv_b, lin_w, lin_b, out, T, B);
}

// Round 8
// 190.630 us; speedup vs baseline: 1.0590x; 1.0590x over previous
//
#include <hip/hip_runtime.h>
#include <math.h>

// Round 14: kill same-phase dependencies (R12/R13 proved neither VALU nor
// LDS throughput is binding -> latency/serialization bound).
//   1. Re-lagged schedule: every phase reads ONLY prior-phase LDS data.
//        wave0 phase g: enc steps 6g+6..6g+11 (one full group ahead), then
//                       conv steps 6g..6g+3 (4 bit-reads hoisted to top).
//        wave1 phase g: conv steps 6g+4,6g+5 (feeds NEXT phase's lin),
//                       lin steps 6g-6..6g-1 (all prior-phase s_p).
//      Slot live-spans <=12 consecutive mod 16 -> disjoint (16-deep bufs).
//   2. lin loads software-pipelined (load k+1 during math k, named structs).
//   3. quad-reduce via DPP quad_perm (VALU; rocPRIM idiom) instead of
//      3x ds_bpermute -> shuffles leave the DS pipe / lgkm chain.
//      Sum order unchanged: (((own + xor1) + xor2) + xor3) + lbias.
// Layouts identical to R13 (uint4 s_bits, interleaved-pair s_p, paired lw2).
// Requires T % 6 == 0, T >= 18.

typedef float v2f __attribute__((ext_vector_type(2)));

#define DPPQ(x, ctrl) \
    __int_as_float(__builtin_amdgcn_mov_dpp(__float_as_int(x), (ctrl), 0xf, 0xf, true))

__global__ __launch_bounds__(128, 4) void snn_step_kernel(
    const float* __restrict__ x,       // [B,1,15,15]
    const float* __restrict__ conv_w,  // [2,1,4,4]
    const float* __restrict__ conv_b,  // [2]
    const float* __restrict__ lin_w,   // [10,72]
    const float* __restrict__ lin_b,   // [10]
    float* __restrict__ out,           // spk_out[B,10] ++ mem_rec[T,B,10] ++ spk_rec[T,B,10]
    int T, int B)
{
    const int b   = blockIdx.x;
    const int tid = threadIdx.x;
    const int w   = tid & 63;
    const int wv  = tid >> 6;   // 0 = enc + 4conv, 1 = 2conv + lin + dec

    __shared__ float    s_linw[720];
    __shared__ float    s_linb[10];
    __shared__ float4   s_lut[4][32];    // [ky][5-bit row bits] -> 4 partial sums
    __shared__ uint4    s_bits4[16][8];  // entries 0..5 used: [py] = words py..py+3
    __shared__ float    s_p[16][80];     // pair j at [20*(j/9) + 2*(j%9)]

    // ---- cooperative staging (128 threads) ----
    for (int j = tid; j < 720; j += 128) s_linw[j] = lin_w[j];
    if (tid < 10) s_linb[tid] = lin_b[tid];
    {
        const int ky = tid >> 5, n = tid & 31;
        float s00 = 0.f, s01 = 0.f, s10 = 0.f, s11 = 0.f;
#pragma unroll
        for (int kx = 0; kx < 4; ++kx) {
            const float w0 = conv_w[ky * 4 + kx];        // ch0
            const float w1 = conv_w[16 + ky * 4 + kx];   // ch1
            if ((n >> kx) & 1)       { s00 += w0; s01 += w1; }  // dx = 0
            if ((n >> (kx + 1)) & 1) { s10 += w0; s11 += w1; }  // dx = 1
        }
        s_lut[ky][n] = make_float4(s00, s01, s10, s11);
    }
    __syncthreads();

    // ===== encoder state (wave0 only; wave1 lanes hold zeros), packed =====
    v2f ve01 = (v2f){0.f, 0.f}, ve23 = (v2f){0.f, 0.f};
    v2f cur01, cur23;
    {
        const int jrow = w >> 4, col = w & 15;
        float c[4];
#pragma unroll
        for (int k = 0; k < 4; ++k) {
            const int  row = 4 * k + jrow;
            const bool act = (col < 15) && (row < 15) && (wv == 0);
            c[k] = act ? __fmul_rn(x[(size_t)b * 225 + row * 15 + col], 10.0f) : 0.f;
        }
        cur01 = (v2f){c[0], c[1]};
        cur23 = (v2f){c[2], c[3]};
    }

    // enc word-pack lane params: lanes 0..23 write word jword of the slot
    const int  jword   = (w >> 2) + (w & 3);   // 0..8 (8 -> pad, zeroed)
    const bool wr_bits = (w < 24);

    // ===== conv lane params (used by both waves) =====
    const bool convlane = (w < 36);
    const int  py = w / 6, px = w - 6 * py;
    const int  wordsel = py;                 // entry py = words py..py+2 (+pad)
    const int  shx = 2 * px, shx16 = shx + 16;
    const int  poff = 20 * (w / 9) + 2 * (w - 9 * (w / 9));  // pair write offset
    const v2f  cb2 = (v2f){conv_b[0], conv_b[1]};

    // ===== lin/decoder lane params (wave1) =====
    const int lo = w >> 2, lq = w & 3;
    v2f lw2[9];   // lw2[t] = {W[lo][9lq+t], W[lo][36+9lq+t]} (interleaved pairs)
#pragma unroll
    for (int t = 0; t < 9; ++t) {
        int i0 = lo * 72 + 9 * lq + t;
        int i1 = i0 + 36;
        lw2[t] = (v2f){s_linw[i0 < 720 ? i0 : 719],
                       s_linw[i1 < 720 ? i1 : 719]};   // clamp for lanes >= 40
    }
    const float lbias = s_linb[lo < 10 ? lo : 0];
    float v = 0.f, i_syn = 0.f, sc = 0.f;
    float svv[6], svs[6];
    const size_t BO = (size_t)B * 10;
    float* mp  = out + BO + (size_t)b * 10 + lo;
    float* spp = out + BO + (size_t)T * BO + (size_t)b * 10 + lo;

    // encoder step (packed update) + ballot word-pack -> s_bits4[slot]
    auto enc_pack = [&](int slot) {
        const v2f tenth = (v2f){0.1f, 0.1f};
        v2f vn01 = ve01 + (cur01 - ve01) * tenth;   // pk sub/mul/add: IEEE per half
        v2f vn23 = ve23 + (cur23 - ve23) * tenth;
        bool sp0 = (vn01.x > 1.0f);
        bool sp1 = (vn01.y > 1.0f);
        bool sp2 = (vn23.x > 1.0f);
        bool sp3 = (vn23.y > 1.0f);
        unsigned long long bal0 = __ballot(sp0);
        unsigned long long bal1 = __ballot(sp1);
        unsigned long long bal2 = __ballot(sp2);
        unsigned long long bal3 = __ballot(sp3);
        ve01 = (v2f){sp0 ? 0.f : vn01.x, sp1 ? 0.f : vn01.y};
        ve23 = (v2f){sp2 ? 0.f : vn23.x, sp3 ? 0.f : vn23.y};
        // wave-uniform ballots; lane picks word jword
        const int jh = jword >> 1;                  // 0..4
        unsigned long long m01 = (jh & 1) ? bal1 : bal0;
        unsigned long long m23 = (jh & 1) ? bal3 : bal2;
        unsigned long long m   = (jh & 2) ? m23 : m01;
        unsigned word = (unsigned)((jword & 1) ? (m >> 32) : m);
        word = (jword < 8) ? word : 0u;             // entry 5's pad word
        if (wr_bits) ((unsigned*)&s_bits4[slot][0])[w] = word;
    };

    // conv LUT compute from pre-read words -> interleaved pair in s_p[slot]
    auto conv_compute = [&](int slot, unsigned wb0, unsigned wb1, unsigned wb2) {
        const int i0 = (wb0 >> shx)   & 31;
        const int i1 = (wb0 >> shx16) & 31;
        const int i2 = (wb1 >> shx)   & 31;
        const int i3 = (wb1 >> shx16) & 31;
        const int i4 = (wb2 >> shx)   & 31;

        const float4 f0 = s_lut[0][i0];
        const float4 f1 = s_lut[1][i1];
        const float4 f2 = s_lut[2][i2];
        const float4 f3 = s_lut[3][i3];
        const float4 g0 = s_lut[0][i1];
        const float4 g1 = s_lut[1][i2];
        const float4 g2 = s_lut[2][i3];
        const float4 g3 = s_lut[3][i4];

        v2f a00 = (v2f){f0.x, f0.y};  a00 += (v2f){f1.x, f1.y};
        a00 += (v2f){f2.x, f2.y};     a00 += (v2f){f3.x, f3.y};
        v2f a01 = (v2f){f0.z, f0.w};  a01 += (v2f){f1.z, f1.w};
        a01 += (v2f){f2.z, f2.w};     a01 += (v2f){f3.z, f3.w};
        v2f a10 = (v2f){g0.x, g0.y};  a10 += (v2f){g1.x, g1.y};
        a10 += (v2f){g2.x, g2.y};     a10 += (v2f){g3.x, g3.y};
        v2f a11 = (v2f){g0.z, g0.w};  a11 += (v2f){g1.z, g1.w};
        a11 += (v2f){g2.z, g2.w};     a11 += (v2f){g3.z, g3.w};

        v2f mraw = __builtin_elementwise_max(
                       __builtin_elementwise_max(a00, a01),
                       __builtin_elementwise_max(a10, a11));
        v2f m2 = mraw + cb2;   // bias after max: rn(x+b) monotone -> exact

        *(v2f*)&s_p[slot][poff] = m2;   // one ds_write_b64: pair {ch0, ch1}
    };

    struct LinLd { float4 q0, q1, q2, q3; v2f q4; };

    auto lin_load = [&](int s) {
        LinLd L;
        const float* pbase = &s_p[s & 15][lq * 20];
        L.q0 = *(const float4*)(pbase + 0);
        L.q1 = *(const float4*)(pbase + 4);
        L.q2 = *(const float4*)(pbase + 8);
        L.q3 = *(const float4*)(pbase + 12);
        L.q4 = *(const v2f*)(pbase + 16);
        return L;
    };

    // linear math (packed fma, DPP quad-reduce) + decoder; deferred slot k
    auto lin_math = [&](const LinLd& L, int k) {
        v2f pacc = (v2f){0.f, 0.f};
        pacc = __builtin_elementwise_fma(lw2[0], (v2f){L.q0.x, L.q0.y}, pacc);
        pacc = __builtin_elementwise_fma(lw2[1], (v2f){L.q0.z, L.q0.w}, pacc);
        pacc = __builtin_elementwise_fma(lw2[2], (v2f){L.q1.x, L.q1.y}, pacc);
        pacc = __builtin_elementwise_fma(lw2[3], (v2f){L.q1.z, L.q1.w}, pacc);
        pacc = __builtin_elementwise_fma(lw2[4], (v2f){L.q2.x, L.q2.y}, pacc);
        pacc = __builtin_elementwise_fma(lw2[5], (v2f){L.q2.z, L.q2.w}, pacc);
        pacc = __builtin_elementwise_fma(lw2[6], (v2f){L.q3.x, L.q3.y}, pacc);
        pacc = __builtin_elementwise_fma(lw2[7], (v2f){L.q3.z, L.q3.w}, pacc);
        pacc = __builtin_elementwise_fma(lw2[8], L.q4, pacc);
        float partial = __fadd_rn(pacc.x, pacc.y);

        // quad reduce via DPP quad_perm (VALU): xor1=177, xor2=78, xor3=27
        float p1 = DPPQ(partial, 177);
        float p2 = DPPQ(partial, 78);
        float p3 = DPPQ(partial, 27);
        float lin = __fadd_rn(
            __fadd_rn(__fadd_rn(__fadd_rn(partial, p1), p2), p3), lbias);

        float vd  = __fadd_rn(v, __fmul_rn(0.1f, __fsub_rn(i_syn, v)));
        float id  = __fsub_rn(i_syn, __fmul_rn(0.2f, i_syn));
        float spk = (vd > 1.0f) ? 1.0f : 0.0f;
        v = (vd > 1.0f) ? 0.0f : vd;
        sc += spk;
        svv[k] = v;
        svs[k] = spk;
        i_syn = __fadd_rn(id, lin);
    };

    auto issue_stores = [&]() {
        if (lq == 0 && lo < 10) {
#pragma unroll
            for (int k = 0; k < 6; ++k) {
                mp[(size_t)k * BO]  = svv[k];
                spp[(size_t)k * BO] = svs[k];
            }
        }
        mp  += 6 * BO;
        spp += 6 * BO;
    };

    // ---- prologue: enc steps 0..5 -> bits slots 0..5 ----
    if (wv == 0) {
        enc_pack(0); enc_pack(1); enc_pack(2);
        enc_pack(3); enc_pack(4); enc_pack(5);
    }
    __syncthreads();

    const int NG = T / 6;   // T % 6 == 0, T >= 18

    for (int g = 0; g < NG; ++g) {
        const int base = 6 * g;
        if (wv == 0) {
            // hoisted bit reads for conv steps base..base+3 (prior phase)
            uint4 bb0 = make_uint4(0,0,0,0), bb1 = bb0, bb2 = bb0, bb3 = bb0;
            if (convlane) {
                bb0 = s_bits4[(base + 0) & 15][wordsel];
                bb1 = s_bits4[(base + 1) & 15][wordsel];
                bb2 = s_bits4[(base + 2) & 15][wordsel];
                bb3 = s_bits4[(base + 3) & 15][wordsel];
            }
            // encoder one full group ahead: steps base+6..base+11
            enc_pack((base + 6)  & 15);
            enc_pack((base + 7)  & 15);
            enc_pack((base + 8)  & 15);
            enc_pack((base + 9)  & 15);
            enc_pack((base + 10) & 15);
            enc_pack((base + 11) & 15);
            if (convlane) {
                conv_compute((base + 0) & 15, bb0.x, bb0.y, bb0.z);
                conv_compute((base + 1) & 15, bb1.x, bb1.y, bb1.z);
                conv_compute((base + 2) & 15, bb2.x, bb2.y, bb2.z);
                conv_compute((base + 3) & 15, bb3.x, bb3.y, bb3.z);
            }
        } else {
            // bit reads for conv steps base+4, base+5 (prior phase data)
            uint4 ba = make_uint4(0,0,0,0), bc = ba;
            if (convlane) {
                ba = s_bits4[(base + 4) & 15][wordsel];
                bc = s_bits4[(base + 5) & 15][wordsel];
            }
            if (g >= 2) issue_stores();              // flush lin batch g-1
            if (convlane) {
                conv_compute((base + 4) & 15, ba.x, ba.y, ba.z);  // feeds phase g+1
                conv_compute((base + 5) & 15, bc.x, bc.y, bc.z);
            }
            if (g >= 1) {
                const int pb = base - 6;             // lin steps pb..pb+5 (prior phases)
                LinLd A0 = lin_load(pb + 0);
                LinLd A1 = lin_load(pb + 1);
                lin_math(A0, 0);
                LinLd A2 = lin_load(pb + 2);
                lin_math(A1, 1);
                LinLd A3 = lin_load(pb + 3);
                lin_math(A2, 2);
                LinLd A4 = lin_load(pb + 4);
                lin_math(A3, 3);
                LinLd A5 = lin_load(pb + 5);
                lin_math(A4, 4);
                lin_math(A5, 5);
            }
        }
        __syncthreads();
    }

    // ---- epilogue (wave1): flush batch NG-1, lin T-6..T-1, flush, sc ----
    if (wv == 1) {
        issue_stores();                              // steps T-12..T-7
        const int pb = T - 6;                        // s_p all written pre-barrier
        LinLd A0 = lin_load(pb + 0);
        LinLd A1 = lin_load(pb + 1);
        lin_math(A0, 0);
        LinLd A2 = lin_load(pb + 2);
        lin_math(A1, 1);
        LinLd A3 = lin_load(pb + 3);
        lin_math(A2, 2);
        LinLd A4 = lin_load(pb + 4);
        lin_math(A3, 3);
        LinLd A5 = lin_load(pb + 5);
        lin_math(A4, 4);
        lin_math(A5, 5);
        issue_stores();                              // steps T-6..T-1
        if (lq == 0 && lo < 10) out[(size_t)b * 10 + lo] = sc;
    }
}

extern "C" void kernel_launch(void* const* d_in, const int* in_sizes, int n_in,
                              void* d_out, int out_size, void* d_ws, size_t ws_size,
                              hipStream_t stream) {
    const float* x      = (const float*)d_in[0];
    const float* conv_w = (const float*)d_in[1];
    const float* conv_b = (const float*)d_in[2];
    const float* lin_w  = (const float*)d_in[3];
    const float* lin_b  = (const float*)d_in[4];
    float* out = (float*)d_out;

    const int B = in_sizes[0] / 225;             // x is [B,1,15,15]
    const int T = (out_size / (B * 10) - 1) / 2; // out = B*10 * (1 + 2T); T=300

    snn_step_kernel<<<B, 128, 0, stream>>>(x, conv_w, conv_b, lin_w, lin_b, out, T, B);
}

// Round 9
// 190.629 us; speedup vs baseline: 1.0591x; 1.0000x over previous
//
#include <hip/hip_runtime.h>
#include <math.h>

// Round 15: R14 (133us) scaled to G=12 steps/phase. R14 proved the limiter is
// serialization (de-phasing deps bought 9.5us where instr cuts bought 0).
// Remaining non-issue time = barrier convoy (50 barriers) + phase-boundary
// bubbles. G=12 halves barriers (25) and doubles per-phase independent work:
//   wave0 phase g: 8 hoisted bit-reads (steps 12g..12g+7) -> 12 enc
//                  (steps 12g+12..12g+23, skipped at g=NG-1) -> 8 conv.
//   wave1 phase g: 4 bit-reads (12g+8..12g+11) -> flush stores batch g-1 ->
//                  4 conv -> 12 lin (loads pipelined 1-deep), dec scan.
// Buffers 32-deep; slot windows disjoint mod 32 (w0 bits W{12..23}+12g vs
// reads {0..7}+12g, w1 {8..11}+12g; s_p w0 W{0..7}, w1 W{8..11}, reads
// {20..31} mod 32). LDS ~19.3KB -> 8 blocks/CU. Load split 8+4 keeps waves
// balanced (~568/~560 slots). FP chains byte-identical to R14.
// Requires T % 12 == 0, T >= 24.

typedef float v2f __attribute__((ext_vector_type(2)));

#define DPPQ(x, ctrl) \
    __int_as_float(__builtin_amdgcn_mov_dpp(__float_as_int(x), (ctrl), 0xf, 0xf, true))

__global__ __launch_bounds__(128, 4) void snn_step_kernel(
    const float* __restrict__ x,       // [B,1,15,15]
    const float* __restrict__ conv_w,  // [2,1,4,4]
    const float* __restrict__ conv_b,  // [2]
    const float* __restrict__ lin_w,   // [10,72]
    const float* __restrict__ lin_b,   // [10]
    float* __restrict__ out,           // spk_out[B,10] ++ mem_rec[T,B,10] ++ spk_rec[T,B,10]
    int T, int B)
{
    const int b   = blockIdx.x;
    const int tid = threadIdx.x;
    const int w   = tid & 63;
    const int wv  = tid >> 6;   // 0 = enc + 8conv, 1 = 4conv + lin + dec

    __shared__ float    s_linw[720];
    __shared__ float    s_linb[10];
    __shared__ float4   s_lut[4][32];    // [ky][5-bit row bits] -> 4 partial sums
    __shared__ uint4    s_bits4[32][8];  // entries 0..5 used: [py] = words py..py+3
    __shared__ float    s_p[32][80];     // pair j at [20*(j/9) + 2*(j%9)]

    // ---- cooperative staging (128 threads) ----
    for (int j = tid; j < 720; j += 128) s_linw[j] = lin_w[j];
    if (tid < 10) s_linb[tid] = lin_b[tid];
    {
        const int ky = tid >> 5, n = tid & 31;
        float s00 = 0.f, s01 = 0.f, s10 = 0.f, s11 = 0.f;
#pragma unroll
        for (int kx = 0; kx < 4; ++kx) {
            const float w0 = conv_w[ky * 4 + kx];        // ch0
            const float w1 = conv_w[16 + ky * 4 + kx];   // ch1
            if ((n >> kx) & 1)       { s00 += w0; s01 += w1; }  // dx = 0
            if ((n >> (kx + 1)) & 1) { s10 += w0; s11 += w1; }  // dx = 1
        }
        s_lut[ky][n] = make_float4(s00, s01, s10, s11);
    }
    __syncthreads();

    // ===== encoder state (wave0 only; wave1 lanes hold zeros), packed =====
    v2f ve01 = (v2f){0.f, 0.f}, ve23 = (v2f){0.f, 0.f};
    v2f cur01, cur23;
    {
        const int jrow = w >> 4, col = w & 15;
        float c[4];
#pragma unroll
        for (int k = 0; k < 4; ++k) {
            const int  row = 4 * k + jrow;
            const bool act = (col < 15) && (row < 15) && (wv == 0);
            c[k] = act ? __fmul_rn(x[(size_t)b * 225 + row * 15 + col], 10.0f) : 0.f;
        }
        cur01 = (v2f){c[0], c[1]};
        cur23 = (v2f){c[2], c[3]};
    }

    // enc word-pack lane params: lanes 0..23 write word jword of the slot
    const int  jword   = (w >> 2) + (w & 3);   // 0..8 (8 -> pad, zeroed)
    const bool wr_bits = (w < 24);

    // ===== conv lane params (used by both waves) =====
    const bool convlane = (w < 36);
    const int  py = w / 6, px = w - 6 * py;
    const int  wordsel = py;                 // entry py = words py..py+2 (+pad)
    const int  shx = 2 * px, shx16 = shx + 16;
    const int  poff = 20 * (w / 9) + 2 * (w - 9 * (w / 9));  // pair write offset
    const v2f  cb2 = (v2f){conv_b[0], conv_b[1]};

    // ===== lin/decoder lane params (wave1) =====
    const int lo = w >> 2, lq = w & 3;
    v2f lw2[9];   // lw2[t] = {W[lo][9lq+t], W[lo][36+9lq+t]} (interleaved pairs)
#pragma unroll
    for (int t = 0; t < 9; ++t) {
        int i0 = lo * 72 + 9 * lq + t;
        int i1 = i0 + 36;
        lw2[t] = (v2f){s_linw[i0 < 720 ? i0 : 719],
                       s_linw[i1 < 720 ? i1 : 719]};   // clamp for lanes >= 40
    }
    const float lbias = s_linb[lo < 10 ? lo : 0];
    float v = 0.f, i_syn = 0.f, sc = 0.f;
    float svv[12], svs[12];
    const size_t BO = (size_t)B * 10;
    float* mp  = out + BO + (size_t)b * 10 + lo;
    float* spp = out + BO + (size_t)T * BO + (size_t)b * 10 + lo;

    // encoder step (packed update) + ballot word-pack -> s_bits4[slot]
    auto enc_pack = [&](int slot) {
        const v2f tenth = (v2f){0.1f, 0.1f};
        v2f vn01 = ve01 + (cur01 - ve01) * tenth;   // pk sub/mul/add: IEEE per half
        v2f vn23 = ve23 + (cur23 - ve23) * tenth;
        bool sp0 = (vn01.x > 1.0f);
        bool sp1 = (vn01.y > 1.0f);
        bool sp2 = (vn23.x > 1.0f);
        bool sp3 = (vn23.y > 1.0f);
        unsigned long long bal0 = __ballot(sp0);
        unsigned long long bal1 = __ballot(sp1);
        unsigned long long bal2 = __ballot(sp2);
        unsigned long long bal3 = __ballot(sp3);
        ve01 = (v2f){sp0 ? 0.f : vn01.x, sp1 ? 0.f : vn01.y};
        ve23 = (v2f){sp2 ? 0.f : vn23.x, sp3 ? 0.f : vn23.y};
        // wave-uniform ballots; lane picks word jword
        const int jh = jword >> 1;                  // 0..4
        unsigned long long m01 = (jh & 1) ? bal1 : bal0;
        unsigned long long m23 = (jh & 1) ? bal3 : bal2;
        unsigned long long m   = (jh & 2) ? m23 : m01;
        unsigned word = (unsigned)((jword & 1) ? (m >> 32) : m);
        word = (jword < 8) ? word : 0u;             // entry 5's pad word
        if (wr_bits) ((unsigned*)&s_bits4[slot][0])[w] = word;
    };

    // conv LUT compute from pre-read words -> interleaved pair in s_p[slot]
    auto conv_compute = [&](int slot, unsigned wb0, unsigned wb1, unsigned wb2) {
        const int i0 = (wb0 >> shx)   & 31;
        const int i1 = (wb0 >> shx16) & 31;
        const int i2 = (wb1 >> shx)   & 31;
        const int i3 = (wb1 >> shx16) & 31;
        const int i4 = (wb2 >> shx)   & 31;

        const float4 f0 = s_lut[0][i0];
        const float4 f1 = s_lut[1][i1];
        const float4 f2 = s_lut[2][i2];
        const float4 f3 = s_lut[3][i3];
        const float4 g0 = s_lut[0][i1];
        const float4 g1 = s_lut[1][i2];
        const float4 g2 = s_lut[2][i3];
        const float4 g3 = s_lut[3][i4];

        v2f a00 = (v2f){f0.x, f0.y};  a00 += (v2f){f1.x, f1.y};
        a00 += (v2f){f2.x, f2.y};     a00 += (v2f){f3.x, f3.y};
        v2f a01 = (v2f){f0.z, f0.w};  a01 += (v2f){f1.z, f1.w};
        a01 += (v2f){f2.z, f2.w};     a01 += (v2f){f3.z, f3.w};
        v2f a10 = (v2f){g0.x, g0.y};  a10 += (v2f){g1.x, g1.y};
        a10 += (v2f){g2.x, g2.y};     a10 += (v2f){g3.x, g3.y};
        v2f a11 = (v2f){g0.z, g0.w};  a11 += (v2f){g1.z, g1.w};
        a11 += (v2f){g2.z, g2.w};     a11 += (v2f){g3.z, g3.w};

        v2f mraw = __builtin_elementwise_max(
                       __builtin_elementwise_max(a00, a01),
                       __builtin_elementwise_max(a10, a11));
        v2f m2 = mraw + cb2;   // bias after max: rn(x+b) monotone -> exact

        *(v2f*)&s_p[slot][poff] = m2;   // one ds_write_b64: pair {ch0, ch1}
    };

    struct LinLd { float4 q0, q1, q2, q3; v2f q4; };

    auto lin_load = [&](int s) {
        LinLd L;
        const float* pbase = &s_p[s & 31][lq * 20];
        L.q0 = *(const float4*)(pbase + 0);
        L.q1 = *(const float4*)(pbase + 4);
        L.q2 = *(const float4*)(pbase + 8);
        L.q3 = *(const float4*)(pbase + 12);
        L.q4 = *(const v2f*)(pbase + 16);
        return L;
    };

    // linear math (packed fma, DPP quad-reduce) + decoder; deferred slot k
    auto lin_math = [&](const LinLd& L, int k) {
        v2f pacc = (v2f){0.f, 0.f};
        pacc = __builtin_elementwise_fma(lw2[0], (v2f){L.q0.x, L.q0.y}, pacc);
        pacc = __builtin_elementwise_fma(lw2[1], (v2f){L.q0.z, L.q0.w}, pacc);
        pacc = __builtin_elementwise_fma(lw2[2], (v2f){L.q1.x, L.q1.y}, pacc);
        pacc = __builtin_elementwise_fma(lw2[3], (v2f){L.q1.z, L.q1.w}, pacc);
        pacc = __builtin_elementwise_fma(lw2[4], (v2f){L.q2.x, L.q2.y}, pacc);
        pacc = __builtin_elementwise_fma(lw2[5], (v2f){L.q2.z, L.q2.w}, pacc);
        pacc = __builtin_elementwise_fma(lw2[6], (v2f){L.q3.x, L.q3.y}, pacc);
        pacc = __builtin_elementwise_fma(lw2[7], (v2f){L.q3.z, L.q3.w}, pacc);
        pacc = __builtin_elementwise_fma(lw2[8], L.q4, pacc);
        float partial = __fadd_rn(pacc.x, pacc.y);

        // quad reduce via DPP quad_perm (VALU): xor1=177, xor2=78, xor3=27
        float p1 = DPPQ(partial, 177);
        float p2 = DPPQ(partial, 78);
        float p3 = DPPQ(partial, 27);
        float lin = __fadd_rn(
            __fadd_rn(__fadd_rn(__fadd_rn(partial, p1), p2), p3), lbias);

        float vd  = __fadd_rn(v, __fmul_rn(0.1f, __fsub_rn(i_syn, v)));
        float id  = __fsub_rn(i_syn, __fmul_rn(0.2f, i_syn));
        float spk = (vd > 1.0f) ? 1.0f : 0.0f;
        v = (vd > 1.0f) ? 0.0f : vd;
        sc += spk;
        svv[k] = v;
        svs[k] = spk;
        i_syn = __fadd_rn(id, lin);
    };

    auto issue_stores = [&]() {
        if (lq == 0 && lo < 10) {
#pragma unroll
            for (int k = 0; k < 12; ++k) {
                mp[(size_t)k * BO]  = svv[k];
                spp[(size_t)k * BO] = svs[k];
            }
        }
        mp  += 12 * BO;
        spp += 12 * BO;
    };

    // lin batch: 12 steps pb..pb+11, loads pipelined one ahead
    auto lin_batch = [&](int pb) {
        LinLd cur = lin_load(pb);
#pragma unroll
        for (int k = 0; k < 11; ++k) {
            LinLd nxt = lin_load(pb + k + 1);
            lin_math(cur, k);
            cur = nxt;
        }
        lin_math(cur, 11);
    };

    // ---- prologue: enc steps 0..11 -> bits slots 0..11 ----
    if (wv == 0) {
#pragma unroll
        for (int k = 0; k < 12; ++k) enc_pack(k);
    }
    __syncthreads();

    const int NG = T / 12;   // T % 12 == 0, T >= 24

    for (int g = 0; g < NG; ++g) {
        const int base = 12 * g;
        if (wv == 0) {
            // hoisted bit reads for conv steps base..base+7 (prior phase)
            uint4 bb[8];
#pragma unroll
            for (int k = 0; k < 8; ++k)
                bb[k] = convlane ? s_bits4[(base + k) & 31][wordsel]
                                 : make_uint4(0, 0, 0, 0);
            // encoder one full phase ahead: steps base+12..base+23
            if (g < NG - 1) {
#pragma unroll
                for (int k = 0; k < 12; ++k) enc_pack((base + 12 + k) & 31);
            }
            if (convlane) {
#pragma unroll
                for (int k = 0; k < 8; ++k)
                    conv_compute((base + k) & 31, bb[k].x, bb[k].y, bb[k].z);
            }
        } else {
            // bit reads for conv steps base+8..base+11 (prior phase data)
            uint4 bc[4];
#pragma unroll
            for (int k = 0; k < 4; ++k)
                bc[k] = convlane ? s_bits4[(base + 8 + k) & 31][wordsel]
                                 : make_uint4(0, 0, 0, 0);
            if (g >= 2) issue_stores();              // flush lin batch g-1
            if (convlane) {
#pragma unroll
                for (int k = 0; k < 4; ++k)          // feeds phase g+1's lin
                    conv_compute((base + 8 + k) & 31, bc[k].x, bc[k].y, bc[k].z);
            }
            if (g >= 1) lin_batch(base - 12);        // lin steps (prior phases)
        }
        __syncthreads();
    }

    // ---- epilogue (wave1): flush batch NG-1, lin T-12..T-1, flush, sc ----
    if (wv == 1) {
        issue_stores();                              // steps T-24..T-13
        lin_batch(T - 12);                           // s_p all written pre-barrier
        issue_stores();                              // steps T-12..T-1
        if (lq == 0 && lo < 10) out[(size_t)b * 10 + lo] = sc;
    }
}

extern "C" void kernel_launch(void* const* d_in, const int* in_sizes, int n_in,
                              void* d_out, int out_size, void* d_ws, size_t ws_size,
                              hipStream_t stream) {
    const float* x      = (const float*)d_in[0];
    const float* conv_w = (const float*)d_in[1];
    const float* conv_b = (const float*)d_in[2];
    const float* lin_w  = (const float*)d_in[3];
    const float* lin_b  = (const float*)d_in[4];
    float* out = (float*)d_out;

    const int B = in_sizes[0] / 225;             // x is [B,1,15,15]
    const int T = (out_size / (B * 10) - 1) / 2; // out = B*10 * (1 + 2T); T=300

    snn_step_kernel<<<B, 128, 0, stream>>>(x, conv_w, conv_b, lin_w, lin_b, out, T, B);
}

// Round 10
// 188.857 us; speedup vs baseline: 1.0690x; 1.0094x over previous
//
#include <hip/hip_runtime.h>
#include <math.h>

// Round 16: time-parallel rewrite. Key fact: encoder resets ve to EXACTLY
// 0.0f and cur is constant, so the fp32 iterate sequence after each reset is
// bitwise identical -> each pixel's spike train is exactly periodic:
// spike(t) <=> (t+1) % K == 0, K = first-spike index+1 from simulating the
// identical fp32 recurrence once (cur<=1.0f provably never spikes: vn<cur in
// RN arithmetic). So enc+conv+lin are parallel across t; only the 10-wide
// decoder scan is serial.
// One kernel, 256 threads (4 waves), 2 barriers total:
//   phase A: LUT build + per-wave period sim (early-exit ballot loop) -> s_K
//   phase B: wave wv runs chunk t in [wv*T/4, +T/4) independently:
//            counters -> 4 ballots -> in-register word selects (3 consecutive
//            words span exactly 2 ballots) -> R14 conv-LUT -> per-wave s_p
//            (dbuf, lin lags 1 step) -> R14 lin+DPP -> s_lin[t][10] in LDS
//   phase C: wave0 decoder scan over s_lin + all global stores.
// conv/lin/decoder FP chains byte-identical to R14/R15 (which passed).
// Requires T % 4 == 0, T <= 300.

typedef float v2f __attribute__((ext_vector_type(2)));
typedef unsigned long long u64;

#define DPPQ(x, ctrl) \
    __int_as_float(__builtin_amdgcn_mov_dpp(__float_as_int(x), (ctrl), 0xf, 0xf, true))

__global__ __launch_bounds__(256, 4) void snn_step_kernel(
    const float* __restrict__ x,       // [B,1,15,15]
    const float* __restrict__ conv_w,  // [2,1,4,4]
    const float* __restrict__ conv_b,  // [2]
    const float* __restrict__ lin_w,   // [10,72]
    const float* __restrict__ lin_b,   // [10]
    float* __restrict__ out,           // spk_out[B,10] ++ mem_rec[T,B,10] ++ spk_rec[T,B,10]
    int T, int B)
{
    const int b   = blockIdx.x;
    const int tid = threadIdx.x;
    const int w   = tid & 63;
    const int wv  = tid >> 6;              // 0..3 = time-chunk index

    __shared__ float4         s_lut[4][32];   // conv row-LUT
    __shared__ unsigned short s_K[4][64];     // spike period per ballot-group/lane
    __shared__ float          s_p[4][2][80];  // per-wave dbuf pooled pairs
    __shared__ float          s_lin[300][10]; // lin outputs for all T steps

    // ---- phase A1: conv LUT (tid < 128) ----
    if (tid < 128) {
        const int ky = tid >> 5, n = tid & 31;
        float s00 = 0.f, s01 = 0.f, s10 = 0.f, s11 = 0.f;
#pragma unroll
        for (int kx = 0; kx < 4; ++kx) {
            const float w0 = conv_w[ky * 4 + kx];        // ch0
            const float w1 = conv_w[16 + ky * 4 + kx];   // ch1
            if ((n >> kx) & 1)       { s00 += w0; s01 += w1; }  // dx = 0
            if ((n >> (kx + 1)) & 1) { s10 += w0; s11 += w1; }  // dx = 1
        }
        s_lut[ky][n] = make_float4(s00, s01, s10, s11);
    }

    // ---- phase A2: period sim — wave wv owns ballot-group wv's 64 pixels ----
    {
        const int  row = 4 * wv + (w >> 4), col = w & 15;
        const bool act = (col < 15) && (row < 15);
        const float cur = act ? __fmul_rn(x[(size_t)b * 225 + row * 15 + col], 10.0f)
                              : 0.f;
        // cur <= 1.0f never spikes: vn = ve + rn(0.1*rn(cur-ve)) < cur (RN)
        int   Kp = (cur > 1.0f) ? 0 : -1;   // -1 = done-never; 0 = searching
        float ve = 0.f;
        int t = 0;
        while (t < T) {
            if (__ballot(Kp == 0) == 0ull) break;
#pragma unroll
            for (int u = 0; u < 4; ++u) {
                float vn = __fadd_rn(ve, __fmul_rn(0.1f, __fsub_rn(cur, ve)));
                bool sp = (vn > 1.0f);
                Kp = (Kp == 0 && sp) ? (t + u + 1) : Kp;
                ve = sp ? 0.f : vn;
            }
            t += 4;
        }
        s_K[wv][w] = (unsigned short)(Kp > 0 ? Kp : 0);   // 0 = never spikes
    }
    __syncthreads();

    // ---- per-lane constants ----
    const bool convlane = (w < 36);
    const int  py = w / 6, px = w - 6 * py;       // pooled coords
    const int  shx = 2 * px, shx16 = shx + 16;
    const int  poff = 20 * (w / 9) + 2 * (w - 9 * (w / 9));
    const v2f  cb2 = (v2f){conv_b[0], conv_b[1]};
    // words py..py+2 span ballots q, q+1 with q = py>>1
    const bool qe0 = ((py >> 1) == 0), qe1 = ((py >> 1) == 1);
    const bool pyodd = (py & 1) != 0;

    const int lo = w >> 2, lq = w & 3;
    v2f lw2[9];   // {W[lo][9lq+t], W[lo][36+9lq+t]}
#pragma unroll
    for (int t = 0; t < 9; ++t) {
        int i0 = lo * 72 + 9 * lq + t;
        int i1 = i0 + 36;
        lw2[t] = (v2f){lin_w[i0 < 720 ? i0 : 719], lin_w[i1 < 720 ? i1 : 719]};
    }
    const float lbias = lin_b[lo < 10 ? lo : 0];

    const int Lc = T >> 2;        // chunk length (75)
    const int t0 = wv * Lc;

    // ---- spike counters: c = K-1 - (t0 % K); spike <=> c == 0 ----
    const int Ka = s_K[0][w], Kb = s_K[1][w], Kc = s_K[2][w], Kd = s_K[3][w];
    int ca = Ka ? (Ka - 1 - t0 % Ka) : 0x0FFFFFFF;
    int cb = Kb ? (Kb - 1 - t0 % Kb) : 0x0FFFFFFF;
    int cc = Kc ? (Kc - 1 - t0 % Kc) : 0x0FFFFFFF;
    int cd = Kd ? (Kd - 1 - t0 % Kd) : 0x0FFFFFFF;

    // counters -> ballots -> this lane's 3 conv words (all in-register)
    auto enc_words = [&](unsigned& wb0, unsigned& wb1, unsigned& wb2) {
        bool sp0 = (ca == 0); u64 b0 = __ballot(sp0); ca = sp0 ? (Ka - 1) : (ca - 1);
        bool sp1 = (cb == 0); u64 b1 = __ballot(sp1); cb = sp1 ? (Kb - 1) : (cb - 1);
        bool sp2 = (cc == 0); u64 b2 = __ballot(sp2); cc = sp2 ? (Kc - 1) : (cc - 1);
        bool sp3 = (cd == 0); u64 b3 = __ballot(sp3); cd = sp3 ? (Kd - 1) : (cd - 1);
        u64 balA = qe0 ? b0 : (qe1 ? b1 : b2);
        u64 balB = qe0 ? b1 : (qe1 ? b2 : b3);
        wb0 = pyodd ? (unsigned)(balA >> 32) : (unsigned)balA;
        wb1 = pyodd ? (unsigned)balB         : (unsigned)(balA >> 32);
        wb2 = pyodd ? (unsigned)(balB >> 32) : (unsigned)balB;
    };

    // conv LUT -> interleaved pair in this wave's s_p[dbuf] (R13/R14 layout)
    auto conv_compute = [&](int dbuf, unsigned wb0, unsigned wb1, unsigned wb2) {
        const int i0 = (wb0 >> shx)   & 31;
        const int i1 = (wb0 >> shx16) & 31;
        const int i2 = (wb1 >> shx)   & 31;
        const int i3 = (wb1 >> shx16) & 31;
        const int i4 = (wb2 >> shx)   & 31;

        const float4 f0 = s_lut[0][i0];
        const float4 f1 = s_lut[1][i1];
        const float4 f2 = s_lut[2][i2];
        const float4 f3 = s_lut[3][i3];
        const float4 g0 = s_lut[0][i1];
        const float4 g1 = s_lut[1][i2];
        const float4 g2 = s_lut[2][i3];
        const float4 g3 = s_lut[3][i4];

        v2f a00 = (v2f){f0.x, f0.y};  a00 += (v2f){f1.x, f1.y};
        a00 += (v2f){f2.x, f2.y};     a00 += (v2f){f3.x, f3.y};
        v2f a01 = (v2f){f0.z, f0.w};  a01 += (v2f){f1.z, f1.w};
        a01 += (v2f){f2.z, f2.w};     a01 += (v2f){f3.z, f3.w};
        v2f a10 = (v2f){g0.x, g0.y};  a10 += (v2f){g1.x, g1.y};
        a10 += (v2f){g2.x, g2.y};     a10 += (v2f){g3.x, g3.y};
        v2f a11 = (v2f){g0.z, g0.w};  a11 += (v2f){g1.z, g1.w};
        a11 += (v2f){g2.z, g2.w};     a11 += (v2f){g3.z, g3.w};

        v2f mraw = __builtin_elementwise_max(
                       __builtin_elementwise_max(a00, a01),
                       __builtin_elementwise_max(a10, a11));
        v2f m2 = mraw + cb2;   // bias after max: rn(x+b) monotone -> exact

        *(v2f*)&s_p[wv][dbuf][poff] = m2;   // one ds_write_b64
    };

    // linear for chunk-step sm1 (reads s_p written last iteration) -> s_lin
    auto lin_step = [&](int sm1) {
        const float* base = &s_p[wv][sm1 & 1][lq * 20];
        float4 q0 = *(const float4*)(base + 0);
        float4 q1 = *(const float4*)(base + 4);
        float4 q2 = *(const float4*)(base + 8);
        float4 q3 = *(const float4*)(base + 12);
        v2f    q4 = *(const v2f*)(base + 16);
        v2f pacc = (v2f){0.f, 0.f};
        pacc = __builtin_elementwise_fma(lw2[0], (v2f){q0.x, q0.y}, pacc);
        pacc = __builtin_elementwise_fma(lw2[1], (v2f){q0.z, q0.w}, pacc);
        pacc = __builtin_elementwise_fma(lw2[2], (v2f){q1.x, q1.y}, pacc);
        pacc = __builtin_elementwise_fma(lw2[3], (v2f){q1.z, q1.w}, pacc);
        pacc = __builtin_elementwise_fma(lw2[4], (v2f){q2.x, q2.y}, pacc);
        pacc = __builtin_elementwise_fma(lw2[5], (v2f){q2.z, q2.w}, pacc);
        pacc = __builtin_elementwise_fma(lw2[6], (v2f){q3.x, q3.y}, pacc);
        pacc = __builtin_elementwise_fma(lw2[7], (v2f){q3.z, q3.w}, pacc);
        pacc = __builtin_elementwise_fma(lw2[8], q4, pacc);
        float partial = __fadd_rn(pacc.x, pacc.y);

        // quad reduce via DPP quad_perm: xor1=177, xor2=78, xor3=27
        float p1 = DPPQ(partial, 177);
        float p2 = DPPQ(partial, 78);
        float p3 = DPPQ(partial, 27);
        float lin = __fadd_rn(
            __fadd_rn(__fadd_rn(__fadd_rn(partial, p1), p2), p3), lbias);

        if (lq == 0 && lo < 10) s_lin[t0 + sm1][lo] = lin;
    };

    // ---- phase B: independent chunk, zero barriers ----
    {   // s = 0 peeled
        unsigned wb0, wb1, wb2;
        enc_words(wb0, wb1, wb2);
        if (convlane) conv_compute(0, wb0, wb1, wb2);
    }
    for (int s = 1; s < Lc; ++s) {
        unsigned wb0, wb1, wb2;
        enc_words(wb0, wb1, wb2);
        if (convlane) conv_compute(s & 1, wb0, wb1, wb2);
        lin_step(s - 1);
    }
    lin_step(Lc - 1);
    __syncthreads();

    // ---- phase C: decoder scan (wave0), exact R14 chain ----
    if (wv == 0) {
        float v = 0.f, i_syn = 0.f, sc = 0.f;
        const int o = (w < 10) ? w : 0;
        const size_t BO = (size_t)B * 10;
        float* mp  = out + BO + (size_t)b * 10 + o;
        float* spp = out + BO + (size_t)T * BO + (size_t)b * 10 + o;
#pragma unroll 4
        for (int t = 0; t < T; ++t) {
            float lv  = s_lin[t][o];
            float vd  = __fadd_rn(v, __fmul_rn(0.1f, __fsub_rn(i_syn, v)));
            float id  = __fsub_rn(i_syn, __fmul_rn(0.2f, i_syn));
            float spk = (vd > 1.0f) ? 1.0f : 0.0f;
            v = (vd > 1.0f) ? 0.0f : vd;
            sc += spk;
            i_syn = __fadd_rn(id, lv);
            if (w < 10) { *mp = v; *spp = spk; }
            mp  += BO;
            spp += BO;
        }
        if (w < 10) out[(size_t)b * 10 + w] = sc;
    }
}

extern "C" void kernel_launch(void* const* d_in, const int* in_sizes, int n_in,
                              void* d_out, int out_size, void* d_ws, size_t ws_size,
                              hipStream_t stream) {
    const float* x      = (const float*)d_in[0];
    const float* conv_w = (const float*)d_in[1];
    const float* conv_b = (const float*)d_in[2];
    const float* lin_w  = (const float*)d_in[3];
    const float* lin_b  = (const float*)d_in[4];
    float* out = (float*)d_out;

    const int B = in_sizes[0] / 225;             // x is [B,1,15,15]
    const int T = (out_size / (B * 10) - 1) / 2; // out = B*10 * (1 + 2T); T=300

    snn_step_kernel<<<B, 256, 0, stream>>>(x, conv_w, conv_b, lin_w, lin_b, out, T, B);
}